// Round 2
// baseline (232.937 us; speedup 1.0000x reference)
//
#include <hip/hip_runtime.h>
#include <hip/hip_cooperative_groups.h>
#include <stdint.h>

namespace cg = cooperative_groups;

typedef __bf16 bf16x8 __attribute__((ext_vector_type(8)));
typedef float f32x4 __attribute__((ext_vector_type(4)));

#define N_ROWS 4096
#define KD 128
#define BM 64
#define CHUNK 128                 // B-chunk rows staged per LDS fill
#define NCHUNK 32                 // 32 chunks of 128 rows
#define GRID_FUSED 1024           // 64 itiles x 16 chunk-pairs = exactly 4 blocks/CU x 256 CU

// Order-preserving float->uint encoding: enc(a) < enc(b) <=> a < b.
#define ENC_POS2 0xC0000000u      // enc(+2.0f) = "no positive yet" (min sentinel)
#define ENC_NEG2 0x3FFFFFFFu      // enc(-2.0f) = "no negative yet" (max sentinel)

__device__ __forceinline__ unsigned enc_f32(float f) {
    union { float f; unsigned u; } v; v.f = f;
    return (v.u & 0x80000000u) ? ~v.u : (v.u | 0x80000000u);
}
__device__ __forceinline__ float dec_f32(unsigned e) {
    union { float f; unsigned u; } v;
    v.u = (e & 0x80000000u) ? (e ^ 0x80000000u) : ~e;
    return v.f;
}

__device__ __forceinline__ unsigned short f32_to_bf16_rne(float f) {
    union { float f; uint32_t u; } v; v.f = f;
    uint32_t u = v.u;
    return (unsigned short)((u + 0x7FFFu + ((u >> 16) & 1u)) >> 16);
}

// XOR-swizzled LDS index for uint4 units (validated: kills bank conflicts).
__device__ __forceinline__ int swz(int row, int c) { return row * 16 + (c ^ (row & 15)); }
__device__ __forceinline__ int swzL(int L) { return (L & ~15) | ((L & 15) ^ ((L >> 4) & 15)); }

// ---- Phase 0: one wave per row, L2-normalize -> bf16 RNE, pack 2/lane.
// Also seeds the hp/hn sentinels for this block's 4 rows (no ticket anywhere).
__device__ __forceinline__ void normalize_rows(const float* __restrict__ E,
                                               unsigned short* __restrict__ out,
                                               unsigned* __restrict__ hp,
                                               unsigned* __restrict__ hn,
                                               int bid, int tid) {
    const int r0 = bid * 4;
    if (tid < 4) { hp[r0 + tid] = ENC_POS2; hn[r0 + tid] = ENC_NEG2; }
    const int wave = tid >> 6;
    const int lane = tid & 63;
    const int row = r0 + wave;
    const float2 v = *(const float2*)&E[row * KD + lane * 2];
    float s = v.x * v.x + v.y * v.y;
#pragma unroll
    for (int m = 1; m < 64; m <<= 1) s += __shfl_xor(s, m, 64);
    float inv = 0.0f;
    if (s > 0.0f) {
        inv = rsqrtf(s);
        inv = inv * (1.5f - 0.5f * s * inv * inv);  // Newton step: ~1e-7 rel err
    }
    const unsigned short a = f32_to_bf16_rne(v.x * inv);
    const unsigned short b = f32_to_bf16_rne(v.y * inv);
    ((uint32_t*)out)[row * (KD / 2) + lane] = ((uint32_t)b << 16) | a;
}

// ---- Phase 1: 64-row I-tile x two 128-row B-chunks. Whole chunk staged to
// swizzled LDS (32 KB), MFMA + fused min/max epilogue, 16-lane reduce, then
// ONE encoded atomicMin/Max per (row, chunk-pair): 16 per row total, spread
// over 8192 addresses — fire-and-forget, no returns, no hot address.
__device__ __forceinline__ void gram_tile(const unsigned short* __restrict__ Ebits,
                                          const int* __restrict__ labels,
                                          unsigned* __restrict__ hp,
                                          unsigned* __restrict__ hn,
                                          uint4* Bs4, int* ljs,
                                          int itile, int cpair, int tid) {
    const int ibase = itile * BM;
    const int wave = tid >> 6, lane = tid & 63;
    const int quad = lane >> 4, l15 = lane & 15;
    const int igb = ibase + wave * 16 + quad * 4;  // row base for this lane's accs

    // A fragments: one-time global gather (shared by both chunks).
    bf16x8 afrag[4];
    {
        const uint4* asrc = (const uint4*)Ebits;
        const int arow = ibase + wave * 16 + l15;
#pragma unroll
        for (int s = 0; s < 4; ++s) afrag[s] = *(const bf16x8*)&asrc[arow * 16 + s * 4 + quad];
    }
    int li_lab[4];
#pragma unroll
    for (int r = 0; r < 4; ++r) li_lab[r] = labels[igb + r];

    float minpos[4] = {2.0f, 2.0f, 2.0f, 2.0f};   // dots in [-1,1]; 2.0 = "no positive"
    float maxneg[4] = {-2.0f, -2.0f, -2.0f, -2.0f};

#pragma unroll
    for (int cc = 0; cc < 2; ++cc) {
        const int cbase = (cpair * 2 + cc) * CHUNK;
        // Stage whole B-chunk: 8 coalesced uint4/thread -> swizzled LDS.
        {
            const uint4* src = (const uint4*)(Ebits + (size_t)cbase * KD);
#pragma unroll
            for (int it = 0; it < 8; ++it) {
                const int L = it * 256 + tid;
                Bs4[swzL(L)] = src[L];
            }
        }
        if (tid < CHUNK) ljs[tid] = labels[cbase + tid];
        __syncthreads();

        // Pure ds_read + MFMA + epilogue stream: 8 j-tiles, no barriers.
#pragma unroll
        for (int t = 0; t < 8; ++t) {
            f32x4 acc = {0.f, 0.f, 0.f, 0.f};
#pragma unroll
            for (int s = 0; s < 4; ++s) {
                const bf16x8 bfrag = *(const bf16x8*)&Bs4[swz(t * 16 + l15, s * 4 + quad)];
                acc = __builtin_amdgcn_mfma_f32_16x16x32_bf16(afrag[s], bfrag, acc, 0, 0, 0);
            }
            // C/D layout: col = lane&15 (j), row = quad*4 + reg (i)  [m89/m91]
            const int jg = cbase + t * 16 + l15;
            const int lj = ljs[t * 16 + l15];
#pragma unroll
            for (int r = 0; r < 4; ++r) {
                const float d = acc[r];
                const bool same = (lj == li_lab[r]);
                const float dp = (same && (igb + r != jg)) ? d : 2.0f;
                const float dn = same ? -2.0f : d;
                minpos[r] = fminf(minpos[r], dp);
                maxneg[r] = fmaxf(maxneg[r], dn);
            }
        }
        __syncthreads();  // guard LDS restage (trailing one is harmless)
    }

    // Reduce across the 16 col-lanes of each quad; rows live in (quad,reg).
#pragma unroll
    for (int m = 1; m < 16; m <<= 1) {
#pragma unroll
        for (int r = 0; r < 4; ++r) {
            minpos[r] = fminf(minpos[r], __shfl_xor(minpos[r], m, 64));
            maxneg[r] = fmaxf(maxneg[r], __shfl_xor(maxneg[r], m, 64));
        }
    }
    if (l15 == 0) {
#pragma unroll
        for (int r = 0; r < 4; ++r) {
            atomicMin(&hp[igb + r], enc_f32(minpos[r]));
            atomicMax(&hn[igb + r], enc_f32(maxneg[r]));
        }
    }
}

// ---- Phase 2: one block, 256 threads x 16 rows, agent-scope loads of hp/hn.
__device__ __forceinline__ void finalize_body(const unsigned* __restrict__ hp,
                                              const unsigned* __restrict__ hn,
                                              float* __restrict__ out,
                                              int tid, float* ssum, int* scnt) {
    float sum = 0.f; int cnt = 0;
#pragma unroll
    for (int k = 0; k < 16; ++k) {
        const int row = k * 256 + tid;
        const unsigned ep = __hip_atomic_load(&hp[row], __ATOMIC_RELAXED, __HIP_MEMORY_SCOPE_AGENT);
        const unsigned en = __hip_atomic_load(&hn[row], __ATOMIC_RELAXED, __HIP_MEMORY_SCOPE_AGENT);
        const float mp = dec_f32(ep);   // hardest positive dot (min)
        const float mn = dec_f32(en);   // hardest negative dot (max)
        if (mp < 1.5f && mn > -1.5f) {  // valid: >=1 pos and >=1 neg
            sum += fmaxf(0.f, mn - mp + 0.3f);  // relu(hp_dist - hn_dist + margin)
            ++cnt;
        }
    }
#pragma unroll
    for (int m = 1; m < 64; m <<= 1) {
        sum += __shfl_xor(sum, m, 64);
        cnt += __shfl_xor(cnt, m, 64);
    }
    const int wave = tid >> 6, lane = tid & 63;
    if (lane == 0) { ssum[wave] = sum; scnt[wave] = cnt; }
    __syncthreads();
    if (tid == 0) {
        const float S = ssum[0] + ssum[1] + ssum[2] + ssum[3];
        const int C = scnt[0] + scnt[1] + scnt[2] + scnt[3];
        out[0] = S / (float)(C > 0 ? C : 1);
    }
}

// ---- Single cooperative kernel: normalize -> grid.sync -> gram -> grid.sync
// -> finalize. 1024 blocks = exactly 4/CU (LDS 32.8 KB, VGPR capped by
// __launch_bounds__(256,4)) so cooperative residency validation passes.
__global__ __launch_bounds__(256, 4) void fused_kernel(const float* __restrict__ E,
                                                       const int* __restrict__ labels,
                                                       unsigned short* __restrict__ ebits,
                                                       unsigned* __restrict__ hp,
                                                       unsigned* __restrict__ hn,
                                                       float* __restrict__ out) {
    __shared__ uint4 Bs4[CHUNK * (KD / 8)];  // 32 KB
    __shared__ int ljs[CHUNK];               // 512 B
    __shared__ float ssum[4];
    __shared__ int scnt[4];

    const int tid = threadIdx.x;
    normalize_rows(E, ebits, hp, hn, blockIdx.x, tid);

    cg::this_grid().sync();   // ebits + hp/hn sentinels visible device-wide

    gram_tile(ebits, labels, hp, hn, Bs4, ljs, blockIdx.x & 63, blockIdx.x >> 6, tid);

    cg::this_grid().sync();   // all atomics folded

    if (blockIdx.x == 0) finalize_body(hp, hn, out, tid, ssum, scnt);
}

// ---- Fallback path (plain dispatches) in case cooperative launch is
// rejected under graph capture: identical device code, kernel boundaries
// provide the ordering instead of grid.sync.
__global__ __launch_bounds__(256) void normalize_kernel(const float* __restrict__ E,
                                                        unsigned short* __restrict__ out,
                                                        unsigned* __restrict__ hp,
                                                        unsigned* __restrict__ hn) {
    normalize_rows(E, out, hp, hn, blockIdx.x, threadIdx.x);
}

__global__ __launch_bounds__(256, 4) void gram_kernel(const unsigned short* __restrict__ Ebits,
                                                      const int* __restrict__ labels,
                                                      unsigned* __restrict__ hp,
                                                      unsigned* __restrict__ hn) {
    __shared__ uint4 Bs4[CHUNK * (KD / 8)];
    __shared__ int ljs[CHUNK];
    gram_tile(Ebits, labels, hp, hn, Bs4, ljs, blockIdx.x & 63, blockIdx.x >> 6, threadIdx.x);
}

__global__ __launch_bounds__(256) void finalize_kernel(const unsigned* __restrict__ hp,
                                                       const unsigned* __restrict__ hn,
                                                       float* __restrict__ out) {
    __shared__ float ssum[4];
    __shared__ int scnt[4];
    finalize_body(hp, hn, out, threadIdx.x, ssum, scnt);
}

extern "C" void kernel_launch(void* const* d_in, const int* in_sizes, int n_in,
                              void* d_out, int out_size, void* d_ws, size_t ws_size,
                              hipStream_t stream) {
    const float* E = (const float*)d_in[0];
    const int* labels = (const int*)d_in[1];

    unsigned short* ebits = (unsigned short*)d_ws;                       // 1 MiB
    unsigned* hp = (unsigned*)((char*)d_ws + (size_t)N_ROWS * KD * 2);   // 16 KiB
    unsigned* hn = hp + N_ROWS;                                          // 16 KiB
    float* out = (float*)d_out;

    void* args[] = {(void*)&E, (void*)&labels, (void*)&ebits,
                    (void*)&hp, (void*)&hn, (void*)&out};
    hipError_t err = hipLaunchCooperativeKernel((const void*)fused_kernel,
                                                dim3(GRID_FUSED), dim3(256),
                                                args, 0, stream);
    if (err != hipSuccess) {
        (void)hipGetLastError();  // clear sticky error, take the 3-dispatch path
        normalize_kernel<<<GRID_FUSED, 256, 0, stream>>>(E, ebits, hp, hn);
        gram_kernel<<<GRID_FUSED, 256, 0, stream>>>(ebits, labels, hp, hn);
        finalize_kernel<<<1, 256, 0, stream>>>(hp, hn, out);
    }
}

// Round 3
// 83.174 us; speedup vs baseline: 2.8006x; 2.8006x over previous
//
#include <hip/hip_runtime.h>
#include <stdint.h>

typedef __bf16 bf16x8 __attribute__((ext_vector_type(8)));
typedef float f32x4 __attribute__((ext_vector_type(4)));

#define N_ROWS 4096
#define KD 128
#define BM 64
#define CHUNK 128                 // B-chunk rows staged per LDS fill
#define GRID_GRAM 1024            // 64 itiles x 16 chunk-pairs
#define NGROUP 32                 // hierarchical ticket: 32 groups of 32 blocks

// Order-preserving float->uint encoding: enc(a) < enc(b) <=> a < b.
#define ENC_POS2 0xC0000000u      // enc(+2.0f) = "no positive yet" (min sentinel)
#define ENC_NEG2 0x3FFFFFFFu      // enc(-2.0f) = "no negative yet" (max sentinel)

__device__ __forceinline__ unsigned enc_f32(float f) {
    union { float f; unsigned u; } v; v.f = f;
    return (v.u & 0x80000000u) ? ~v.u : (v.u | 0x80000000u);
}
__device__ __forceinline__ float dec_f32(unsigned e) {
    union { float f; unsigned u; } v;
    v.u = (e & 0x80000000u) ? (e ^ 0x80000000u) : ~e;
    return v.f;
}

__device__ __forceinline__ unsigned short f32_to_bf16_rne(float f) {
    union { float f; uint32_t u; } v; v.f = f;
    uint32_t u = v.u;
    return (unsigned short)((u + 0x7FFFu + ((u >> 16) & 1u)) >> 16);
}

// XOR-swizzled LDS index for uint4 units (validated: kills bank conflicts).
__device__ __forceinline__ int swz(int row, int c) { return row * 16 + (c ^ (row & 15)); }
__device__ __forceinline__ int swzL(int L) { return (L & ~15) | ((L & 15) ^ ((L >> 4) & 15)); }

// ---- Dispatch 1: one wave per row, L2-normalize -> bf16 RNE, pack 2/lane.
// Seeds hp/hn sentinels for this block's 4 rows; block 0 zeroes the tickets.
__global__ __launch_bounds__(256) void normalize_kernel(const float* __restrict__ E,
                                                        unsigned short* __restrict__ out,
                                                        unsigned* __restrict__ hp,
                                                        unsigned* __restrict__ hn,
                                                        unsigned* __restrict__ tickets) {
    const int r0 = blockIdx.x * 4;
    if (threadIdx.x < 4) { hp[r0 + threadIdx.x] = ENC_POS2; hn[r0 + threadIdx.x] = ENC_NEG2; }
    if (blockIdx.x == 0 && threadIdx.x < NGROUP + 1) tickets[threadIdx.x] = 0u;

    const int wave = threadIdx.x >> 6;
    const int lane = threadIdx.x & 63;
    const int row = r0 + wave;
    const float2 v = *(const float2*)&E[row * KD + lane * 2];
    float s = v.x * v.x + v.y * v.y;
#pragma unroll
    for (int m = 1; m < 64; m <<= 1) s += __shfl_xor(s, m, 64);
    float inv = 0.0f;
    if (s > 0.0f) {
        inv = rsqrtf(s);
        inv = inv * (1.5f - 0.5f * s * inv * inv);  // Newton step: ~1e-7 rel err
    }
    const unsigned short a = f32_to_bf16_rne(v.x * inv);
    const unsigned short b = f32_to_bf16_rne(v.y * inv);
    ((uint32_t*)out)[row * (KD / 2) + lane] = ((uint32_t)b << 16) | a;
}

// ---- Dispatch 2: 64-row I-tile x two 128-row B-chunks per block (1024 blocks,
// 4/CU). MFMA + fused min/max epilogue; per-row results folded into global
// hp/hn via encoded fire-and-forget atomicMin/Max (8192 addresses, no hot
// line). Then a HIERARCHICAL ticket (32 groups of 32 -> 1 root) elects the
// last block, which finalizes the loss in-kernel. Critical-path RMW chain
// ~64 ops (vs 2048 flat in round 1, which cost ~22 us).
__global__ __launch_bounds__(256, 4) void gram_kernel(const unsigned short* __restrict__ Ebits,
                                                      const int* __restrict__ labels,
                                                      unsigned* __restrict__ hp,
                                                      unsigned* __restrict__ hn,
                                                      unsigned* __restrict__ tickets,
                                                      float* __restrict__ out) {
    __shared__ uint4 Bs4[CHUNK * (KD / 8)];  // 32 KB
    __shared__ int ljs[CHUNK];               // 512 B
    __shared__ unsigned s_last;
    __shared__ float ssum[4];
    __shared__ int scnt[4];

    const int tid = threadIdx.x;
    const int itile = blockIdx.x & 63;
    const int cpair = blockIdx.x >> 6;
    const int ibase = itile * BM;

    const int wave = tid >> 6, lane = tid & 63;
    const int quad = lane >> 4, l15 = lane & 15;
    const int igb = ibase + wave * 16 + quad * 4;  // row base for this lane's accs

    // A fragments: one-time global gather (shared by both chunks).
    bf16x8 afrag[4];
    {
        const uint4* asrc = (const uint4*)Ebits;
        const int arow = ibase + wave * 16 + l15;
#pragma unroll
        for (int s = 0; s < 4; ++s) afrag[s] = *(const bf16x8*)&asrc[arow * 16 + s * 4 + quad];
    }
    int li_lab[4];
#pragma unroll
    for (int r = 0; r < 4; ++r) li_lab[r] = labels[igb + r];

    float minpos[4] = {2.0f, 2.0f, 2.0f, 2.0f};   // dots in [-1,1]; 2.0 = "no positive"
    float maxneg[4] = {-2.0f, -2.0f, -2.0f, -2.0f};

#pragma unroll
    for (int cc = 0; cc < 2; ++cc) {
        const int cbase = (cpair * 2 + cc) * CHUNK;
        // Stage whole B-chunk: 8 coalesced uint4/thread -> swizzled LDS.
        {
            const uint4* src = (const uint4*)(Ebits + (size_t)cbase * KD);
#pragma unroll
            for (int it = 0; it < 8; ++it) {
                const int L = it * 256 + tid;
                Bs4[swzL(L)] = src[L];
            }
        }
        if (tid < CHUNK) ljs[tid] = labels[cbase + tid];
        __syncthreads();

        // Pure ds_read + MFMA + epilogue stream: 8 j-tiles, no barriers.
#pragma unroll
        for (int t = 0; t < 8; ++t) {
            f32x4 acc = {0.f, 0.f, 0.f, 0.f};
#pragma unroll
            for (int s = 0; s < 4; ++s) {
                const bf16x8 bfrag = *(const bf16x8*)&Bs4[swz(t * 16 + l15, s * 4 + quad)];
                acc = __builtin_amdgcn_mfma_f32_16x16x32_bf16(afrag[s], bfrag, acc, 0, 0, 0);
            }
            // C/D layout: col = lane&15 (j), row = quad*4 + reg (i)  [m89/m91]
            const int jg = cbase + t * 16 + l15;
            const int lj = ljs[t * 16 + l15];
#pragma unroll
            for (int r = 0; r < 4; ++r) {
                const float d = acc[r];
                const bool same = (lj == li_lab[r]);
                const float dp = (same && (igb + r != jg)) ? d : 2.0f;
                const float dn = same ? -2.0f : d;
                minpos[r] = fminf(minpos[r], dp);
                maxneg[r] = fmaxf(maxneg[r], dn);
            }
        }
        __syncthreads();  // guard LDS restage
    }

    // Reduce across the 16 col-lanes of each quad; rows live in (quad,reg).
#pragma unroll
    for (int m = 1; m < 16; m <<= 1) {
#pragma unroll
        for (int r = 0; r < 4; ++r) {
            minpos[r] = fminf(minpos[r], __shfl_xor(minpos[r], m, 64));
            maxneg[r] = fmaxf(maxneg[r], __shfl_xor(maxneg[r], m, 64));
        }
    }
    if (l15 == 0) {
#pragma unroll
        for (int r = 0; r < 4; ++r) {
            atomicMin(&hp[igb + r], enc_f32(minpos[r]));
            atomicMax(&hn[igb + r], enc_f32(maxneg[r]));
        }
    }

    // Hierarchical ticket. __syncthreads drains each wave's atomics (vmcnt)
    // before tid 0 proceeds; threadfence gives release ordering.
    __syncthreads();
    if (tid == 0) {
        __threadfence();
        const unsigned o = atomicAdd(&tickets[blockIdx.x >> 5], 1u);  // group of 32
        unsigned lastv = 0u;
        if (o == 31u) {
            const unsigned o2 = atomicAdd(&tickets[NGROUP], 1u);      // root
            lastv = (o2 == (unsigned)(NGROUP - 1)) ? 1u : 0u;
        }
        s_last = lastv;
    }
    __syncthreads();
    if (s_last == 0u) return;

    // ---- Last block: finalize. 256 threads x 16 rows, agent-scope loads.
    __threadfence();
    float sum = 0.f; int cnt = 0;
#pragma unroll
    for (int k = 0; k < 16; ++k) {
        const int row = k * 256 + tid;
        const unsigned ep = __hip_atomic_load(&hp[row], __ATOMIC_RELAXED, __HIP_MEMORY_SCOPE_AGENT);
        const unsigned en = __hip_atomic_load(&hn[row], __ATOMIC_RELAXED, __HIP_MEMORY_SCOPE_AGENT);
        const float mp = dec_f32(ep);   // hardest positive dot (min)
        const float mn = dec_f32(en);   // hardest negative dot (max)
        if (mp < 1.5f && mn > -1.5f) {  // valid: >=1 pos and >=1 neg
            sum += fmaxf(0.f, mn - mp + 0.3f);  // relu(hp_dist - hn_dist + margin)
            ++cnt;
        }
    }
#pragma unroll
    for (int m = 1; m < 64; m <<= 1) {
        sum += __shfl_xor(sum, m, 64);
        cnt += __shfl_xor(cnt, m, 64);
    }
    if (lane == 0) { ssum[wave] = sum; scnt[wave] = cnt; }
    __syncthreads();
    if (tid == 0) {
        const float S = ssum[0] + ssum[1] + ssum[2] + ssum[3];
        const int C = scnt[0] + scnt[1] + scnt[2] + scnt[3];
        out[0] = S / (float)(C > 0 ? C : 1);
    }
}

extern "C" void kernel_launch(void* const* d_in, const int* in_sizes, int n_in,
                              void* d_out, int out_size, void* d_ws, size_t ws_size,
                              hipStream_t stream) {
    const float* E = (const float*)d_in[0];
    const int* labels = (const int*)d_in[1];

    unsigned short* ebits = (unsigned short*)d_ws;                       // 1 MiB
    unsigned* hp = (unsigned*)((char*)d_ws + (size_t)N_ROWS * KD * 2);   // 16 KiB
    unsigned* hn = hp + N_ROWS;                                          // 16 KiB
    unsigned* tickets = hn + N_ROWS;                                     // 33 words
    float* out = (float*)d_out;

    normalize_kernel<<<N_ROWS / 4, 256, 0, stream>>>(E, ebits, hp, hn, tickets);
    gram_kernel<<<GRID_GRAM, 256, 0, stream>>>(ebits, labels, hp, hn, tickets, out);
}

// Round 4
// 72.269 us; speedup vs baseline: 3.2232x; 1.1509x over previous
//
#include <hip/hip_runtime.h>
#include <stdint.h>

typedef __bf16 bf16x8 __attribute__((ext_vector_type(8)));
typedef float f32x4 __attribute__((ext_vector_type(4)));

#define N_ROWS 4096
#define KD 128
#define BM 128                    // I-tile rows: each bfrag ds_read feeds 2 MFMAs
#define NCHUNK 32
#define CHUNK 128                 // whole chunk staged once; ONE barrier per block
#define NBLOCKS (32 * NCHUNK)     // 1024 blocks = 32 I-tiles x 32 chunks = exactly 4/CU
#define FIN_BLOCKS 64

__device__ __forceinline__ unsigned short f32_to_bf16_rne(float f) {
    union { float f; uint32_t u; } v; v.f = f;
    uint32_t u = v.u;
    return (unsigned short)((u + 0x7FFFu + ((u >> 16) & 1u)) >> 16);
}

// XOR-swizzled LDS index for uint4 units: (row, kblock c) -> row*16 + (c ^ (row&15)).
// Involution within each 16-uint4 row: used BOTH as the read swizzle and as the
// inverse-source permutation for linear-dest global_load_lds (rule-21 pattern).
__device__ __forceinline__ int swz(int row, int c) { return row * 16 + (c ^ (row & 15)); }
__device__ __forceinline__ int swzL(int L) { return (L & ~15) | ((L & 15) ^ ((L >> 4) & 15)); }

// One wave per row: L2-normalize, round to bf16 (RNE), pack 2 elems/lane.
// Block 0 zeroes finalize's accumulators + ticket.
__global__ __launch_bounds__(256) void normalize_kernel(const float* __restrict__ E,
                                                        unsigned short* __restrict__ out,
                                                        unsigned* __restrict__ ctrl) {
    if (blockIdx.x == 0 && threadIdx.x < 3) ctrl[threadIdx.x] = 0u;
    const int wave = threadIdx.x >> 6;
    const int lane = threadIdx.x & 63;
    const int row = blockIdx.x * 4 + wave;
    const float2 v = *(const float2*)&E[row * KD + lane * 2];
    float s = v.x * v.x + v.y * v.y;
#pragma unroll
    for (int m = 1; m < 64; m <<= 1) s += __shfl_xor(s, m, 64);
    float inv = 0.0f;
    if (s > 0.0f) {
        inv = rsqrtf(s);
        inv = inv * (1.5f - 0.5f * s * inv * inv);  // Newton step: ~1e-7 rel err
    }
    const unsigned short a = f32_to_bf16_rne(v.x * inv);
    const unsigned short b = f32_to_bf16_rne(v.y * inv);
    ((uint32_t*)out)[row * (KD / 2) + lane] = ((uint32_t)b << 16) | a;
}

// 1024 blocks = 32 I-tiles x 32 chunks, exactly 4 blocks/CU. Whole 128-row
// B-chunk DMA'd to swizzled LDS via global_load_lds (linear dest, inverse-
// swizzled per-lane source). Each wave owns TWO 16-row m-blocks so every
// bfrag ds_read_b128 feeds 2 MFMAs -> LDS-read bytes per unit work halved
// vs BM=64 (the dominant gram pipe: was ~1 MB/CU, now ~512 KB/CU).
__global__ __launch_bounds__(256, 4) void gram_kernel(const unsigned short* __restrict__ Ebits,
                                                      const int* __restrict__ labels,
                                                      float2* __restrict__ partials) {
    __shared__ uint4 Bs4[CHUNK * (KD / 8)];  // 32 KB
    __shared__ int ljs[CHUNK];               // 512 B

    const int tid = threadIdx.x;
    const int itile = blockIdx.x & 31;
    const int chunk = blockIdx.x >> 5;
    const int ibase = itile * BM;
    const int cbase = chunk * CHUNK;

    const int wave = tid >> 6, lane = tid & 63;
    const int quad = lane >> 4, l15 = lane & 15;

    // Async-stage whole B-chunk: 8 x global_load_lds_dwordx4 per thread-slot.
    // LDS dest linear (wave-uniform base + lane*16); global source pre-swizzled
    // with the same involution the reads use.
    {
        const uint4* src = (const uint4*)(Ebits + (size_t)cbase * KD);
#pragma unroll
        for (int it = 0; it < 8; ++it) {
            const int Ld = it * 256 + wave * 64 + lane;  // linear dest slot
            const int Ls = swzL(Ld);                     // inverse-swizzled source
            __builtin_amdgcn_global_load_lds(
                (const __attribute__((address_space(1))) void*)&src[Ls],
                (__attribute__((address_space(3))) void*)&Bs4[it * 256 + wave * 64],
                16, 0, 0);
        }
    }
    if (tid < CHUNK) ljs[tid] = labels[cbase + tid];

    // A fragments for the wave's two m-blocks: A[m=l15][k = s*32 + quad*8 ..+7].
    bf16x8 afrag[2][4];
    {
        const uint4* asrc = (const uint4*)Ebits;
#pragma unroll
        for (int mb = 0; mb < 2; ++mb) {
            const int arow = ibase + wave * 32 + mb * 16 + l15;
#pragma unroll
            for (int s = 0; s < 4; ++s)
                afrag[mb][s] = *(const bf16x8*)&asrc[arow * 16 + s * 4 + quad];
        }
    }
    int li_lab[2][4];
#pragma unroll
    for (int mb = 0; mb < 2; ++mb)
#pragma unroll
        for (int r = 0; r < 4; ++r)
            li_lab[mb][r] = labels[ibase + wave * 32 + mb * 16 + quad * 4 + r];

    __syncthreads();  // the ONLY barrier (drains gload_lds vmcnt + ds writes)

    float minpos[2][4] = {{2.f, 2.f, 2.f, 2.f}, {2.f, 2.f, 2.f, 2.f}};
    float maxneg[2][4] = {{-2.f, -2.f, -2.f, -2.f}, {-2.f, -2.f, -2.f, -2.f}};

    // Pure ds_read + MFMA + epilogue stream: 8 j-tiles, no barriers.
#pragma unroll
    for (int t = 0; t < 8; ++t) {
        f32x4 acc0 = {0.f, 0.f, 0.f, 0.f};
        f32x4 acc1 = {0.f, 0.f, 0.f, 0.f};
#pragma unroll
        for (int s = 0; s < 4; ++s) {
            const bf16x8 bfrag = *(const bf16x8*)&Bs4[swz(t * 16 + l15, s * 4 + quad)];
            acc0 = __builtin_amdgcn_mfma_f32_16x16x32_bf16(afrag[0][s], bfrag, acc0, 0, 0, 0);
            acc1 = __builtin_amdgcn_mfma_f32_16x16x32_bf16(afrag[1][s], bfrag, acc1, 0, 0, 0);
        }
        // C/D layout: col = lane&15 (j), row = quad*4 + reg (i)  [m89/m91]
        const int jg = cbase + t * 16 + l15;
        const int lj = ljs[t * 16 + l15];
#pragma unroll
        for (int mb = 0; mb < 2; ++mb) {
            const int ig0 = ibase + wave * 32 + mb * 16 + quad * 4;
#pragma unroll
            for (int r = 0; r < 4; ++r) {
                const float d = (mb == 0) ? acc0[r] : acc1[r];
                const bool same = (lj == li_lab[mb][r]);
                const float dp = (same && (ig0 + r != jg)) ? d : 2.0f;
                const float dn = same ? -2.0f : d;
                minpos[mb][r] = fminf(minpos[mb][r], dp);
                maxneg[mb][r] = fmaxf(maxneg[mb][r], dn);
            }
        }
    }

    // Reduce across the 16 col-lanes of each quad; rows live in (mb,quad,reg).
#pragma unroll
    for (int m = 1; m < 16; m <<= 1) {
#pragma unroll
        for (int mb = 0; mb < 2; ++mb)
#pragma unroll
            for (int r = 0; r < 4; ++r) {
                minpos[mb][r] = fminf(minpos[mb][r], __shfl_xor(minpos[mb][r], m, 64));
                maxneg[mb][r] = fmaxf(maxneg[mb][r], __shfl_xor(maxneg[mb][r], m, 64));
            }
    }
    if (l15 == 0) {
#pragma unroll
        for (int mb = 0; mb < 2; ++mb) {
            const int ig0 = ibase + wave * 32 + mb * 16 + quad * 4;
#pragma unroll
            for (int r = 0; r < 4; ++r)
                partials[(ig0 + r) * NCHUNK + chunk] = make_float2(minpos[mb][r], maxneg[mb][r]);
        }
    }
}

// 64 blocks x 64 rows, 4 threads/row (each reads 4 float4 of the row's 32
// partials), shfl-combine, 2 atomicAdds + ticket; last block writes the loss.
__global__ __launch_bounds__(256) void finalize_kernel(const float2* __restrict__ partials,
                                                       float* __restrict__ gsum,
                                                       unsigned* __restrict__ gcnt,
                                                       unsigned* __restrict__ ticket,
                                                       float* __restrict__ out) {
    __shared__ float ssum[4];
    __shared__ int scnt[4];
    __shared__ unsigned s_old;

    const int tid = threadIdx.x;
    const int sub = tid & 3;
    const int row = blockIdx.x * 64 + (tid >> 2);

    const float4* p4 = (const float4*)&partials[row * NCHUNK];  // 16 float4 / row
    float mp = 2.f, mn = -2.f;
#pragma unroll
    for (int k = 0; k < 4; ++k) {
        const float4 v = p4[sub * 4 + k];      // {min,max,min,max}
        mp = fminf(mp, fminf(v.x, v.z));
        mn = fmaxf(mn, fmaxf(v.y, v.w));
    }
    mp = fminf(mp, __shfl_xor(mp, 1, 64)); mp = fminf(mp, __shfl_xor(mp, 2, 64));
    mn = fmaxf(mn, __shfl_xor(mn, 1, 64)); mn = fmaxf(mn, __shfl_xor(mn, 2, 64));

    float sum = 0.f; int cnt = 0;
    if (sub == 0 && mp < 1.5f && mn > -1.5f) {   // valid: >=1 pos and >=1 neg
        sum = fmaxf(0.f, mn - mp + 0.3f);        // relu(hp - hn + margin)
        cnt = 1;
    }
#pragma unroll
    for (int m = 1; m < 64; m <<= 1) {
        sum += __shfl_xor(sum, m, 64);
        cnt += __shfl_xor(cnt, m, 64);
    }
    const int wave = tid >> 6, lane = tid & 63;
    if (lane == 0) { ssum[wave] = sum; scnt[wave] = cnt; }
    __syncthreads();
    if (tid == 0) {
        atomicAdd(gsum, ssum[0] + ssum[1] + ssum[2] + ssum[3]);
        atomicAdd(gcnt, (unsigned)(scnt[0] + scnt[1] + scnt[2] + scnt[3]));
    }
    __syncthreads();                 // drain the adds (vmcnt) before ticket
    if (tid == 0) s_old = atomicAdd(ticket, 1u);
    __syncthreads();
    if (s_old == (unsigned)(FIN_BLOCKS - 1) && tid == 0) {
        const float S = __hip_atomic_load(gsum, __ATOMIC_RELAXED, __HIP_MEMORY_SCOPE_AGENT);
        const unsigned C = __hip_atomic_load(gcnt, __ATOMIC_RELAXED, __HIP_MEMORY_SCOPE_AGENT);
        out[0] = S / (float)(C > 0u ? C : 1u);
    }
}

extern "C" void kernel_launch(void* const* d_in, const int* in_sizes, int n_in,
                              void* d_out, int out_size, void* d_ws, size_t ws_size,
                              hipStream_t stream) {
    const float* E = (const float*)d_in[0];
    const int* labels = (const int*)d_in[1];

    unsigned short* ebits = (unsigned short*)d_ws;                          // 1 MiB
    float2* partials = (float2*)((char*)d_ws + (size_t)N_ROWS * KD * 2);    // 1 MiB
    unsigned* ctrl = (unsigned*)(partials + N_ROWS * NCHUNK);               // [gsum][gcnt][ticket]
    float* gsum = (float*)&ctrl[0];
    unsigned* gcnt = &ctrl[1];
    unsigned* ticket = &ctrl[2];
    float* out = (float*)d_out;

    normalize_kernel<<<N_ROWS / 4, 256, 0, stream>>>(E, ebits, ctrl);
    gram_kernel<<<NBLOCKS, 256, 0, stream>>>(ebits, labels, partials);
    finalize_kernel<<<FIN_BLOCKS, 256, 0, stream>>>(partials, gsum, gcnt, ticket, out);
}